// Round 1
// baseline (177.252 us; speedup 1.0000x reference)
//
#include <hip/hip_runtime.h>
#include <stdint.h>

// Problem constants (N=2, S=2048, E=1024, H=16, D=64)
#define S_LEN 2048
#define EMB 1024
#define NHEADS 16
#define HD 64
#define LOG2E 1.4426950408889634f

typedef __bf16 bf16x8 __attribute__((ext_vector_type(8)));
typedef float f32x4 __attribute__((ext_vector_type(4)));
typedef unsigned short u16;

#define MFMA16(a, b, c) __builtin_amdgcn_mfma_f32_16x16x32_bf16(a, b, c, 0, 0, 0)
#define GLOAD_LDS16(gp, lp)                                        \
  __builtin_amdgcn_global_load_lds(                                \
      (const __attribute__((address_space(1))) unsigned int*)(gp), \
      (__attribute__((address_space(3))) unsigned int*)(lp), 16, 0, 0)

__device__ __forceinline__ u16 bf16r(float x) {
  union { float f; unsigned int u; } c; c.f = x;
  unsigned int u = c.u + 0x7fffu + ((c.u >> 16) & 1u);
  return (u16)(u >> 16);
}

// ---- fp32 -> bf16 convert (vectorized) ----
__global__ void cvt_bf16_kernel(const float* __restrict__ in, u16* __restrict__ out, int n4) {
  int i = blockIdx.x * blockDim.x + threadIdx.x;
  int stride = gridDim.x * blockDim.x;
  for (; i < n4; i += stride) {
    float4 v = ((const float4*)in)[i];
    ushort4 o;
    o.x = bf16r(v.x); o.y = bf16r(v.y); o.z = bf16r(v.z); o.w = bf16r(v.w);
    ((ushort4*)out)[i] = o;
  }
}

// ---- V transpose: v[n][s][h*64+d] fp32 -> vt[n][h][d][s] bf16 ----
__global__ __launch_bounds__(256) void vtrans_kernel(const float* __restrict__ v,
                                                     u16* __restrict__ vt) {
  __shared__ u16 tile[64][65];
  int b = blockIdx.x;                 // n*512 + h*32 + st
  int st = b & 31, h = (b >> 5) & 15, n = b >> 9;
  int t = threadIdx.x;
  int s0 = st * 64;
  int d = t & 63, r4 = t >> 6;
#pragma unroll
  for (int i = 0; i < 16; ++i) {
    int s = r4 + i * 4;
    float x = v[(size_t)(n * S_LEN + s0 + s) * EMB + h * HD + d];
    tile[s][d] = bf16r(x);
  }
  __syncthreads();
#pragma unroll
  for (int i = 0; i < 16; ++i) {
    int dd = r4 + i * 4;
    vt[(size_t)((n * NHEADS + h) * HD + dd) * S_LEN + s0 + d] = tile[d][dd];
  }
}

// ---- mask pre-reduction: flag[n][q][kt] = all(mask[n,0,q,kt*64:(kt+1)*64] != 0) ----
__global__ void maskflag_kernel(const int* __restrict__ mask, unsigned char* __restrict__ fl) {
  int idx = blockIdx.x * 256 + threadIdx.x;  // (n*2048 + q)*32 + kt
  if (idx >= 2 * S_LEN * (S_LEN / 64)) return;
  const int4* mp = ((const int4*)mask) + (size_t)idx * 16;
  int ok = 1;
#pragma unroll
  for (int i = 0; i < 16; ++i) {
    int4 m = mp[i];
    ok &= (m.x != 0) & (m.y != 0) & (m.z != 0) & (m.w != 0);
  }
  fl[idx] = (unsigned char)ok;
}

// ---- flash attention: QTILE=64 (4 waves x 16 rows), KVBLK=64 ----
__global__ __launch_bounds__(256) void attn_kernel(
    const u16* __restrict__ qb, const u16* __restrict__ kbuf,
    const u16* __restrict__ vt, const int* __restrict__ mask,
    const unsigned char* __restrict__ fl, u16* __restrict__ ob) {
  // K tile [64 rows][64 d] and Vt tile [64 d][64 k], both 128B/row, XOR-swizzled
  __shared__ __align__(16) unsigned char kl[64 * 128];
  __shared__ __align__(16) unsigned char vl[64 * 128];
  __shared__ __align__(16) u16 pl[4][16][72];  // per-wave P tile, pad 72 (2-way writes)

  int b = blockIdx.x;  // n*512 + h*32 + qt
  int qt = b & 31, h = (b >> 5) & 15, n = b >> 9;
  int t = threadIdx.x;
  int w = t >> 6, l = t & 63;
  int l16 = l & 15, g = l >> 4;

  // Q fragments in registers (A operand: row = l16, k = g*8+e (+32 for hh=1))
  int qrow = qt * 64 + w * 16 + l16;
  const u16* qp = qb + (size_t)(n * S_LEN + qrow) * EMB + h * HD + g * 8;
  bf16x8 aq0 = *(const bf16x8*)(qp);
  bf16x8 aq1 = *(const bf16x8*)(qp + 32);

  f32x4 zero4 = {0.f, 0.f, 0.f, 0.f};
  f32x4 acc[4];
  float mrun[4], lrun[4];
#pragma unroll
  for (int r = 0; r < 4; ++r) { mrun[r] = -INFINITY; lrun[r] = 0.f; acc[r] = zero4; }

  int row_s = t >> 3;   // staging row 0..31 (+32)
  int cc = t & 7;       // staging 16B-chunk 0..7
  int q0 = qt * 64 + w * 16 + g * 4;  // first of this lane's 4 q-rows

  for (int kt = 0; kt < S_LEN / 64; ++kt) {
    __syncthreads();  // prev-tile reads done before restaging
#pragma unroll
    for (int i = 0; i < 2; ++i) {
      int row = row_s + i * 32;
      int sc = cc ^ (row & 7);  // pre-swizzled source -> swizzled-linear LDS
      const u16* gk = kbuf + (size_t)(n * S_LEN + kt * 64 + row) * EMB + h * HD + sc * 8;
      GLOAD_LDS16(gk, kl + (i * 256 + w * 64) * 16);
      const u16* gv = vt + (size_t)((n * NHEADS + h) * HD + row) * S_LEN + kt * 64 + sc * 8;
      GLOAD_LDS16(gv, vl + (i * 256 + w * 64) * 16);
    }
    __syncthreads();  // staged data visible (vmcnt drained by barrier)

    // S = Q K^T : 4 col-fragments of 16 k-cols each
    f32x4 sf[4];
#pragma unroll
    for (int kb = 0; kb < 4; ++kb) {
      f32x4 z = zero4;
      int row = kb * 16 + l16;
      bf16x8 bk0 = *(const bf16x8*)(kl + row * 128 + ((g * 16) ^ ((row & 7) << 4)));
      z = MFMA16(aq0, bk0, z);
      bf16x8 bk1 = *(const bf16x8*)(kl + row * 128 + ((64 + g * 16) ^ ((row & 7) << 4)));
      z = MFMA16(aq1, bk1, z);
      sf[kb] = z;
    }

    // scaled logits (scale AFTER mask per reference: masked -> -1e20/32)
    float tt[4][4];
#pragma unroll
    for (int kb = 0; kb < 4; ++kb)
#pragma unroll
      for (int r = 0; r < 4; ++r) tt[kb][r] = sf[kb][r] * 0.03125f;

#pragma unroll
    for (int r = 0; r < 4; ++r) {
      unsigned char f = fl[(size_t)(n * S_LEN + q0 + r) * 32 + kt];
      if (f == 0) {  // slow path: per-element mask (never taken for all-ones mask)
#pragma unroll
        for (int kb = 0; kb < 4; ++kb) {
          int m = mask[(size_t)n * S_LEN * S_LEN + (size_t)(q0 + r) * S_LEN + kt * 64 + kb * 16 + l16];
          if (m == 0) tt[kb][r] = -3.125e18f;
        }
      }
    }

    // online softmax; each lane owns rows q0..q0+3; row spread over 16 k-lanes
    float tmax[4];
#pragma unroll
    for (int r = 0; r < 4; ++r)
      tmax[r] = fmaxf(fmaxf(tt[0][r], tt[1][r]), fmaxf(tt[2][r], tt[3][r]));
#pragma unroll
    for (int off = 1; off < 16; off <<= 1)
#pragma unroll
      for (int r = 0; r < 4; ++r) tmax[r] = fmaxf(tmax[r], __shfl_xor(tmax[r], off));

    float corr[4];
#pragma unroll
    for (int r = 0; r < 4; ++r) {
      float Mn = fmaxf(mrun[r], tmax[r]);
      corr[r] = exp2f((mrun[r] - Mn) * LOG2E);
      mrun[r] = Mn;
    }
    float ps[4] = {0.f, 0.f, 0.f, 0.f};
#pragma unroll
    for (int kb = 0; kb < 4; ++kb)
#pragma unroll
      for (int r = 0; r < 4; ++r) {
        float p = exp2f((tt[kb][r] - mrun[r]) * LOG2E);
        ps[r] += p;
        pl[w][g * 4 + r][kb * 16 + l16] = bf16r(p);
      }
#pragma unroll
    for (int off = 1; off < 16; off <<= 1)
#pragma unroll
      for (int r = 0; r < 4; ++r) ps[r] += __shfl_xor(ps[r], off);
#pragma unroll
    for (int r = 0; r < 4; ++r) lrun[r] = lrun[r] * corr[r] + ps[r];
#pragma unroll
    for (int db = 0; db < 4; ++db)
#pragma unroll
      for (int r = 0; r < 4; ++r) acc[db][r] *= corr[r];

    __builtin_amdgcn_wave_barrier();  // order P writes before A-frag reads (same wave)

    // O += P V : A = P from LDS, B = Vt (column-major-in-k)
#pragma unroll
    for (int hh = 0; hh < 2; ++hh) {
      bf16x8 ap = *(const bf16x8*)(&pl[w][l16][hh * 32 + g * 8]);
#pragma unroll
      for (int db = 0; db < 4; ++db) {
        int d = db * 16 + l16;
        bf16x8 bv = *(const bf16x8*)(vl + d * 128 + ((hh * 64 + g * 16) ^ ((d & 7) << 4)));
        acc[db] = MFMA16(ap, bv, acc[db]);
      }
    }
  }

  // epilogue: normalize, write bf16 O[n][q][h*64+d]
#pragma unroll
  for (int db = 0; db < 4; ++db)
#pragma unroll
    for (int r = 0; r < 4; ++r) {
      float o = acc[db][r] / lrun[r];
      int qg = q0 + r;
      ob[(size_t)(n * S_LEN + qg) * EMB + h * HD + db * 16 + l16] = bf16r(o);
    }
}

// ---- output projection: C[4096][1024] = O_bf16 @ W_bf16^T + bias ----
__global__ __launch_bounds__(256) void proj_kernel(
    const u16* __restrict__ A, const u16* __restrict__ Bt,
    const float* __restrict__ bias, float* __restrict__ C) {
  __shared__ __align__(16) unsigned char al[128 * 128];
  __shared__ __align__(16) unsigned char bl[128 * 128];
  int bm = blockIdx.x, bn = blockIdx.y;
  int t = threadIdx.x, w = t >> 6, l = t & 63;
  int l16 = l & 15, g = l >> 4;
  int wm = w >> 1, wn = w & 1;
  f32x4 zero4 = {0.f, 0.f, 0.f, 0.f};
  f32x4 acc[4][4];
#pragma unroll
  for (int m = 0; m < 4; ++m)
#pragma unroll
    for (int nn = 0; nn < 4; ++nn) acc[m][nn] = zero4;
  int row_s = t >> 3, cc = t & 7;

  for (int ks = 0; ks < 16; ++ks) {
    __syncthreads();
#pragma unroll
    for (int i = 0; i < 4; ++i) {
      int row = row_s + i * 32;
      int sc = cc ^ (row & 7);
      const u16* ga = A + (size_t)(bm * 128 + row) * EMB + ks * 64 + sc * 8;
      GLOAD_LDS16(ga, al + (i * 256 + w * 64) * 16);
      const u16* gb = Bt + (size_t)(bn * 128 + row) * EMB + ks * 64 + sc * 8;
      GLOAD_LDS16(gb, bl + (i * 256 + w * 64) * 16);
    }
    __syncthreads();
#pragma unroll
    for (int hh = 0; hh < 2; ++hh) {
      bf16x8 af[4], bfr[4];
#pragma unroll
      for (int m = 0; m < 4; ++m) {
        int row = wm * 64 + m * 16 + l16;
        af[m] = *(const bf16x8*)(al + row * 128 + ((hh * 64 + g * 16) ^ ((row & 7) << 4)));
      }
#pragma unroll
      for (int nn = 0; nn < 4; ++nn) {
        int row = wn * 64 + nn * 16 + l16;
        bfr[nn] = *(const bf16x8*)(bl + row * 128 + ((hh * 64 + g * 16) ^ ((row & 7) << 4)));
      }
#pragma unroll
      for (int m = 0; m < 4; ++m)
#pragma unroll
        for (int nn = 0; nn < 4; ++nn) acc[m][nn] = MFMA16(af[m], bfr[nn], acc[m][nn]);
    }
  }
#pragma unroll
  for (int nn = 0; nn < 4; ++nn) {
    int j = bn * 128 + wn * 64 + nn * 16 + l16;
    float bj = bias[j];
#pragma unroll
    for (int m = 0; m < 4; ++m) {
      int i0 = bm * 128 + wm * 64 + m * 16 + g * 4;
#pragma unroll
      for (int r = 0; r < 4; ++r) C[(size_t)(i0 + r) * EMB + j] = acc[m][nn][r] + bj;
    }
  }
}

extern "C" void kernel_launch(void* const* d_in, const int* in_sizes, int n_in,
                              void* d_out, int out_size, void* d_ws, size_t ws_size,
                              hipStream_t stream) {
  const float* values = (const float*)d_in[0];
  const float* keys = (const float*)d_in[1];
  const float* query = (const float*)d_in[2];
  const int* mask = (const int*)d_in[3];
  const float* W = (const float*)d_in[4];
  const float* bias = (const float*)d_in[5];
  float* out = (float*)d_out;

  // ws layout (bf16 elements): qb, kb, vt, ob : 4,194,304 each; wb : 1,048,576;
  // then 128KB mask flags. Total ~35.8 MB.
  u16* qb = (u16*)d_ws;
  u16* kbuf = qb + 4194304;
  u16* vt = kbuf + 4194304;
  u16* ob = vt + 4194304;
  u16* wb = ob + 4194304;
  unsigned char* fl = (unsigned char*)(wb + 1048576);

  cvt_bf16_kernel<<<1024, 256, 0, stream>>>(query, qb, 1048576);
  cvt_bf16_kernel<<<1024, 256, 0, stream>>>(keys, kbuf, 1048576);
  cvt_bf16_kernel<<<256, 256, 0, stream>>>(W, wb, 262144);
  vtrans_kernel<<<1024, 256, 0, stream>>>(values, vt);
  maskflag_kernel<<<512, 256, 0, stream>>>(mask, fl);
  attn_kernel<<<1024, 256, 0, stream>>>(qb, kbuf, vt, mask, fl, ob);
  proj_kernel<<<dim3(32, 8), 256, 0, stream>>>(ob, wb, bias, out);
}

// Round 2
// 110.126 us; speedup vs baseline: 1.6095x; 1.6095x over previous
//
#include <hip/hip_runtime.h>
#include <stdint.h>

// Problem constants (N=2, S=2048, E=1024, H=16, D=64)
#define S_LEN 2048
#define EMB 1024
#define NHEADS 16
#define HD 64
#define LOG2E 1.4426950408889634f

typedef __bf16 bf16x8 __attribute__((ext_vector_type(8)));
typedef float f32x4 __attribute__((ext_vector_type(4)));
typedef unsigned short u16;

#define MFMA16(a, b, c) __builtin_amdgcn_mfma_f32_16x16x32_bf16(a, b, c, 0, 0, 0)
#define GLOAD_LDS16(gp, lp)                                        \
  __builtin_amdgcn_global_load_lds(                                \
      (const __attribute__((address_space(1))) unsigned int*)(gp), \
      (__attribute__((address_space(3))) unsigned int*)(lp), 16, 0, 0)

__device__ __forceinline__ u16 bf16r(float x) {
  union { float f; unsigned int u; } c; c.f = x;
  unsigned int u = c.u + 0x7fffu + ((c.u >> 16) & 1u);
  return (u16)(u >> 16);
}

__device__ __forceinline__ unsigned int cvt_pk_bf16(float lo, float hi) {
  unsigned int r;
  asm("v_cvt_pk_bf16_f32 %0, %1, %2" : "=v"(r) : "v"(lo), "v"(hi));
  return r;
}

__device__ __forceinline__ float fexp2(float x) {
  float r;
  asm("v_exp_f32 %0, %1" : "=v"(r) : "v"(x));
  return r;
}

// ---- fp32 -> bf16 convert (vectorized, optional scale) ----
__global__ void cvt_bf16_kernel(const float* __restrict__ in, u16* __restrict__ out,
                                int n4, float scale) {
  int i = blockIdx.x * blockDim.x + threadIdx.x;
  int stride = gridDim.x * blockDim.x;
  for (; i < n4; i += stride) {
    float4 v = ((const float4*)in)[i];
    ushort4 o;
    o.x = bf16r(v.x * scale); o.y = bf16r(v.y * scale);
    o.z = bf16r(v.z * scale); o.w = bf16r(v.w * scale);
    ((ushort4*)out)[i] = o;
  }
}

// ---- V transpose: v[n][s][h*64+d] fp32 -> vt[n][h][d][s] bf16 ----
__global__ __launch_bounds__(256) void vtrans_kernel(const float* __restrict__ v,
                                                     u16* __restrict__ vt) {
  __shared__ u16 tile[64][65];
  int b = blockIdx.x;                 // n*512 + h*32 + st
  int st = b & 31, h = (b >> 5) & 15, n = b >> 9;
  int t = threadIdx.x;
  int s0 = st * 64;
  int d = t & 63, r4 = t >> 6;
#pragma unroll
  for (int i = 0; i < 16; ++i) {
    int s = r4 + i * 4;
    float x = v[(size_t)(n * S_LEN + s0 + s) * EMB + h * HD + d];
    tile[s][d] = bf16r(x);
  }
  __syncthreads();
#pragma unroll
  for (int i = 0; i < 16; ++i) {
    int dd = r4 + i * 4;
    vt[(size_t)((n * NHEADS + h) * HD + dd) * S_LEN + s0 + d] = tile[d][dd];
  }
}

// ---- mask pre-reduction: fl2[(n*16+qt)*32+kt] = all(mask[n,0,qt*128:+128,kt*64:+64]!=0) ----
__global__ __launch_bounds__(256) void maskflag2_kernel(const int* __restrict__ mask,
                                                        unsigned char* __restrict__ fl2) {
  int idx = blockIdx.x;  // (n*16+qt)*32 + kt
  int kt = idx & 31, qt = (idx >> 5) & 15, n = idx >> 9;
  int t = threadIdx.x;
  int qr = t >> 1, c8 = t & 1;  // 128 rows x 2 threads/row x 8 int4 each
  const int4* mp = (const int4*)(mask + (size_t)n * S_LEN * S_LEN +
                                 (size_t)(qt * 128 + qr) * S_LEN + kt * 64) + c8 * 8;
  int ok = 1;
#pragma unroll
  for (int i = 0; i < 8; ++i) {
    int4 m = mp[i];
    ok &= (m.x != 0) & (m.y != 0) & (m.z != 0) & (m.w != 0);
  }
  ok = __all(ok);
  __shared__ int s_ok[4];
  if ((t & 63) == 0) s_ok[t >> 6] = ok;
  __syncthreads();
  if (t == 0) fl2[idx] = (unsigned char)(s_ok[0] & s_ok[1] & s_ok[2] & s_ok[3]);
}

// ---- flash attention: 128 q/block (4 waves x 2 subtiles x 16 q), KVBLK=64 ----
// Swapped QK^T (mfma(K,Q) -> S^T): lane owns one q-row => shuffle-free softmax,
// defer-max (threshold 8), contiguous P writes (cvt_pk + ds_write_b64).
__global__ __launch_bounds__(256) void attn_kernel(
    const u16* __restrict__ qb, const u16* __restrict__ kbuf,
    const u16* __restrict__ vt, const int* __restrict__ mask,
    const unsigned char* __restrict__ fl2, u16* __restrict__ ob) {
  __shared__ __align__(16) unsigned char kl[64 * 128];  // K tile [64 k][64 d], swizzled
  __shared__ __align__(16) unsigned char vl[64 * 128];  // Vt tile [64 d][64 k], swizzled
  __shared__ __align__(16) u16 pl[4][2][16][72];        // per wave/u: P[16 q][64 k], pad 72

  int b = blockIdx.x;
  b = (b & 7) * 64 + (b >> 3);  // XCD swizzle: 4 (n,h) pairs per XCD -> K/V L2-resident
  int qt = b & 15, h = (b >> 4) & 15, n = b >> 8;
  int t = threadIdx.x, w = t >> 6, l = t & 63, l16 = l & 15, g = l >> 4;
  int q0w = qt * 128 + w * 32;

  // Q fragments (B-operand of swapped QK): lane l16 = q-col, elems = d
  bf16x8 aq[2][2];
#pragma unroll
  for (int u = 0; u < 2; ++u)
#pragma unroll
    for (int hh = 0; hh < 2; ++hh)
      aq[u][hh] = *(const bf16x8*)(qb + (size_t)(n * S_LEN + q0w + u * 16 + l16) * EMB +
                                   h * HD + hh * 32 + g * 8);

  f32x4 zero4 = {0.f, 0.f, 0.f, 0.f};
  f32x4 acc[2][4];
  float lrun[2] = {0.f, 0.f}, mrun[2] = {0.f, 0.f}, mL[2] = {0.f, 0.f};
#pragma unroll
  for (int u = 0; u < 2; ++u)
#pragma unroll
    for (int db = 0; db < 4; ++db) acc[u][db] = zero4;

  int row_s = t >> 3, cc = t & 7;
  int sc = cc ^ (row_s & 7);  // pre-swizzled source chunk (rows r and r+32 share r&7)
  const u16* gk0 = kbuf + (size_t)(n * S_LEN + row_s) * EMB + h * HD + sc * 8;
  const u16* gv0 = vt + (size_t)((n * NHEADS + h) * HD + row_s) * S_LEN + sc * 8;

  for (int kt = 0; kt < S_LEN / 64; ++kt) {
    __syncthreads();  // prev-tile LDS reads done
    const u16* gk = gk0 + (size_t)kt * 64 * EMB;
    const u16* gv = gv0 + kt * 64;
    GLOAD_LDS16(gk, kl + (w * 64) * 16);
    GLOAD_LDS16(gk + 32 * EMB, kl + (256 + w * 64) * 16);
    GLOAD_LDS16(gv, vl + (w * 64) * 16);
    GLOAD_LDS16(gv + 32 * S_LEN, vl + (256 + w * 64) * 16);
    __syncthreads();  // staged data visible

    // S^T = K Q^T : lane (l16,g) -> S[k=kb*16+g*4+r][q=q0w+u*16+l16]
    f32x4 sf[2][4];
#pragma unroll
    for (int kb = 0; kb < 4; ++kb) {
      int row = kb * 16 + l16;
      const unsigned char* kr = kl + row * 128;
      int sw = (row & 7) << 4;
      bf16x8 bk0 = *(const bf16x8*)(kr + ((g * 16) ^ sw));
      bf16x8 bk1 = *(const bf16x8*)(kr + ((64 + g * 16) ^ sw));
#pragma unroll
      for (int u = 0; u < 2; ++u) {
        f32x4 z = zero4;
        z = MFMA16(bk0, aq[u][0], z);
        z = MFMA16(bk1, aq[u][1], z);
        sf[u][kb] = z;
      }
    }

    unsigned char fflag = fl2[((n * 16 + qt) * 32) + kt];
    if (!fflag) {  // rare: per-element mask, k contiguous per lane -> int4
#pragma unroll
      for (int u = 0; u < 2; ++u) {
        const int* mrow = mask + (size_t)n * S_LEN * S_LEN +
                          (size_t)(q0w + u * 16 + l16) * S_LEN + kt * 64 + g * 4;
#pragma unroll
        for (int kb = 0; kb < 4; ++kb) {
          int4 mm = *(const int4*)(mrow + kb * 16);
          if (mm.x == 0) sf[u][kb][0] = -30.f;
          if (mm.y == 0) sf[u][kb][1] = -30.f;
          if (mm.z == 0) sf[u][kb][2] = -30.f;
          if (mm.w == 0) sf[u][kb][3] = -30.f;
        }
      }
    }

#pragma unroll
    for (int u = 0; u < 2; ++u) {
      // defer-max: in-register max over this lane's 16 values (one q-row)
      float lmax = sf[u][0][0];
#pragma unroll
      for (int kb = 0; kb < 4; ++kb)
#pragma unroll
        for (int r = 0; r < 4; ++r) lmax = fmaxf(lmax, sf[u][kb][r]);
      if (!__all(lmax <= mrun[u] + 8.f)) {  // rare rescale path
        float rmax = fmaxf(lmax, __shfl_xor(lmax, 16));
        rmax = fmaxf(rmax, __shfl_xor(rmax, 32));
        float Mn = fmaxf(mrun[u], rmax);
        float corr = fexp2((mrun[u] - Mn) * LOG2E);
        mrun[u] = Mn;
        mL[u] = Mn * LOG2E;
        lrun[u] *= corr;
#pragma unroll
        for (int r = 0; r < 4; ++r) {
          float ca = __shfl(corr, (l & 48) + (g << 2) + r);
#pragma unroll
          for (int db = 0; db < 4; ++db) acc[u][db][r] *= ca;
        }
      }
      // p = exp(s - m), sum into lane-partial, pack to bf16 pairs
      float p[4][4];
#pragma unroll
      for (int kb = 0; kb < 4; ++kb)
#pragma unroll
        for (int r = 0; r < 4; ++r)
          p[kb][r] = fexp2(fmaf(sf[u][kb][r], LOG2E, -mL[u]));
      float s01 = (p[0][0] + p[0][1]) + (p[0][2] + p[0][3]);
      float s23 = (p[1][0] + p[1][1]) + (p[1][2] + p[1][3]);
      float s45 = (p[2][0] + p[2][1]) + (p[2][2] + p[2][3]);
      float s67 = (p[3][0] + p[3][1]) + (p[3][2] + p[3][3]);
      lrun[u] += (s01 + s23) + (s45 + s67);
#pragma unroll
      for (int kb = 0; kb < 4; ++kb) {
        uint2 pw;
        pw.x = cvt_pk_bf16(p[kb][0], p[kb][1]);
        pw.y = cvt_pk_bf16(p[kb][2], p[kb][3]);
        *(uint2*)(&pl[w][u][l16][kb * 16 + g * 4]) = pw;
      }
    }
    __builtin_amdgcn_wave_barrier();  // order P writes before A-frag reads (same wave)

    // O += P V : V fragments shared across both q-subtiles
#pragma unroll
    for (int hh = 0; hh < 2; ++hh) {
      bf16x8 ap0 = *(const bf16x8*)(&pl[w][0][l16][hh * 32 + g * 8]);
      bf16x8 ap1 = *(const bf16x8*)(&pl[w][1][l16][hh * 32 + g * 8]);
#pragma unroll
      for (int db = 0; db < 4; ++db) {
        int d = db * 16 + l16;
        bf16x8 bv = *(const bf16x8*)(vl + d * 128 + ((hh * 64 + g * 16) ^ ((d & 7) << 4)));
        acc[0][db] = MFMA16(ap0, bv, acc[0][db]);
        acc[1][db] = MFMA16(ap1, bv, acc[1][db]);
      }
    }
  }

  // epilogue: reduce lane-partial sums across g-groups, redistribute to acc rows
#pragma unroll
  for (int u = 0; u < 2; ++u) {
    float s = lrun[u];
    s += __shfl_xor(s, 16);
    s += __shfl_xor(s, 32);
    float rinv[4];
#pragma unroll
    for (int r = 0; r < 4; ++r) {
      float sr = __shfl(s, (l & 48) + (g << 2) + r);
      rinv[r] = 1.f / sr;
    }
#pragma unroll
    for (int db = 0; db < 4; ++db)
#pragma unroll
      for (int r = 0; r < 4; ++r) {
        int qg = q0w + u * 16 + (g << 2) + r;
        ob[(size_t)(n * S_LEN + qg) * EMB + h * HD + db * 16 + l16] =
            bf16r(acc[u][db][r] * rinv[r]);
      }
  }
}

// ---- output projection: C[4096][1024] = O_bf16 @ W_bf16^T + bias ----
__global__ __launch_bounds__(256) void proj_kernel(
    const u16* __restrict__ A, const u16* __restrict__ Bt,
    const float* __restrict__ bias, float* __restrict__ C) {
  __shared__ __align__(16) unsigned char al[128 * 128];
  __shared__ __align__(16) unsigned char bl[128 * 128];
  int bm = blockIdx.x, bn = blockIdx.y;
  int t = threadIdx.x, w = t >> 6, l = t & 63;
  int l16 = l & 15, g = l >> 4;
  int wm = w >> 1, wn = w & 1;
  f32x4 zero4 = {0.f, 0.f, 0.f, 0.f};
  f32x4 acc[4][4];
#pragma unroll
  for (int m = 0; m < 4; ++m)
#pragma unroll
    for (int nn = 0; nn < 4; ++nn) acc[m][nn] = zero4;
  int row_s = t >> 3, cc = t & 7;

  for (int ks = 0; ks < 16; ++ks) {
    __syncthreads();
#pragma unroll
    for (int i = 0; i < 4; ++i) {
      int row = row_s + i * 32;
      int sc = cc ^ (row & 7);
      const u16* ga = A + (size_t)(bm * 128 + row) * EMB + ks * 64 + sc * 8;
      GLOAD_LDS16(ga, al + (i * 256 + w * 64) * 16);
      const u16* gb = Bt + (size_t)(bn * 128 + row) * EMB + ks * 64 + sc * 8;
      GLOAD_LDS16(gb, bl + (i * 256 + w * 64) * 16);
    }
    __syncthreads();
#pragma unroll
    for (int hh = 0; hh < 2; ++hh) {
      bf16x8 af[4], bfr[4];
#pragma unroll
      for (int m = 0; m < 4; ++m) {
        int row = wm * 64 + m * 16 + l16;
        af[m] = *(const bf16x8*)(al + row * 128 + ((hh * 64 + g * 16) ^ ((row & 7) << 4)));
      }
#pragma unroll
      for (int nn = 0; nn < 4; ++nn) {
        int row = wn * 64 + nn * 16 + l16;
        bfr[nn] = *(const bf16x8*)(bl + row * 128 + ((hh * 64 + g * 16) ^ ((row & 7) << 4)));
      }
#pragma unroll
      for (int m = 0; m < 4; ++m)
#pragma unroll
        for (int nn = 0; nn < 4; ++nn) acc[m][nn] = MFMA16(af[m], bfr[nn], acc[m][nn]);
    }
  }
#pragma unroll
  for (int nn = 0; nn < 4; ++nn) {
    int j = bn * 128 + wn * 64 + nn * 16 + l16;
    float bj = bias[j];
#pragma unroll
    for (int m = 0; m < 4; ++m) {
      int i0 = bm * 128 + wm * 64 + m * 16 + g * 4;
#pragma unroll
      for (int r = 0; r < 4; ++r) C[(size_t)(i0 + r) * EMB + j] = acc[m][nn][r] + bj;
    }
  }
}

extern "C" void kernel_launch(void* const* d_in, const int* in_sizes, int n_in,
                              void* d_out, int out_size, void* d_ws, size_t ws_size,
                              hipStream_t stream) {
  const float* values = (const float*)d_in[0];
  const float* keys = (const float*)d_in[1];
  const float* query = (const float*)d_in[2];
  const int* mask = (const int*)d_in[3];
  const float* W = (const float*)d_in[4];
  const float* bias = (const float*)d_in[5];
  float* out = (float*)d_out;

  u16* qb = (u16*)d_ws;
  u16* kbuf = qb + 4194304;
  u16* vt = kbuf + 4194304;
  u16* ob = vt + 4194304;
  u16* wb = ob + 4194304;
  unsigned char* fl2 = (unsigned char*)(wb + 1048576);

  // scale 1/32 folded into Q (exact: power of two)
  cvt_bf16_kernel<<<1024, 256, 0, stream>>>(query, qb, 1048576, 0.03125f);
  cvt_bf16_kernel<<<1024, 256, 0, stream>>>(keys, kbuf, 1048576, 1.0f);
  cvt_bf16_kernel<<<256, 256, 0, stream>>>(W, wb, 262144, 1.0f);
  vtrans_kernel<<<1024, 256, 0, stream>>>(values, vt);
  maskflag2_kernel<<<1024, 256, 0, stream>>>(mask, fl2);
  attn_kernel<<<512, 256, 0, stream>>>(qb, kbuf, vt, mask, fl2, ob);
  proj_kernel<<<dim3(32, 8), 256, 0, stream>>>(ob, wb, bias, out);
}

// Round 3
// 100.468 us; speedup vs baseline: 1.7643x; 1.0961x over previous
//
#include <hip/hip_runtime.h>
#include <stdint.h>

// Problem constants (N=2, S=2048, E=1024, H=16, D=64)
#define S_LEN 2048
#define EMB 1024
#define NHEADS 16
#define HD 64
#define LOG2E 1.4426950408889634f

typedef __bf16 bf16x8 __attribute__((ext_vector_type(8)));
typedef float f32x4 __attribute__((ext_vector_type(4)));
typedef unsigned short u16;

#define MFMA16(a, b, c) __builtin_amdgcn_mfma_f32_16x16x32_bf16(a, b, c, 0, 0, 0)
#define GLOAD_LDS16(gp, lp)                                        \
  __builtin_amdgcn_global_load_lds(                                \
      (const __attribute__((address_space(1))) unsigned int*)(gp), \
      (__attribute__((address_space(3))) unsigned int*)(lp), 16, 0, 0)

__device__ __forceinline__ u16 bf16r(float x) {
  union { float f; unsigned int u; } c; c.f = x;
  unsigned int u = c.u + 0x7fffu + ((c.u >> 16) & 1u);
  return (u16)(u >> 16);
}

__device__ __forceinline__ unsigned int cvt_pk_bf16(float lo, float hi) {
  unsigned int r;
  asm("v_cvt_pk_bf16_f32 %0, %1, %2" : "=v"(r) : "v"(lo), "v"(hi));
  return r;
}

__device__ __forceinline__ float fexp2(float x) {
  float r;
  asm("v_exp_f32 %0, %1" : "=v"(r) : "v"(x));
  return r;
}

// ---- fused preprocessing: V-transpose | K cvt | W cvt | mask flags ----
__global__ __launch_bounds__(256) void prep_kernel(
    const float* __restrict__ values, const float* __restrict__ keys,
    const float* __restrict__ W, const int* __restrict__ mask,
    u16* __restrict__ vt, u16* __restrict__ kb, u16* __restrict__ wb,
    unsigned char* __restrict__ fl2) {
  __shared__ u16 tile[64][65];
  __shared__ int s_ok[4];
  int b = blockIdx.x;
  int t = threadIdx.x;
  if (b < 1024) {
    // V transpose: v[n][s][h*64+d] fp32 -> vt[n][h][d][s] bf16
    int st = b & 31, h = (b >> 5) & 15, n = b >> 9;
    int s0 = st * 64;
    int d = t & 63, r4 = t >> 6;
#pragma unroll
    for (int i = 0; i < 16; ++i) {
      int s = r4 + i * 4;
      float x = values[(size_t)(n * S_LEN + s0 + s) * EMB + h * HD + d];
      tile[s][d] = bf16r(x);
    }
    __syncthreads();
#pragma unroll
    for (int i = 0; i < 16; ++i) {
      int dd = r4 + i * 4;
      vt[(size_t)((n * NHEADS + h) * HD + dd) * S_LEN + s0 + d] = tile[d][dd];
    }
  } else if (b < 2048) {
    // K fp32 -> bf16 (1,048,576 float4)
    int idx = (b - 1024) * 256 + t;
    const float4* in4 = (const float4*)keys;
    ushort4* out4 = (ushort4*)kb;
#pragma unroll
    for (int j = 0; j < 4; ++j) {
      float4 v = in4[idx + j * 262144];
      ushort4 o;
      o.x = bf16r(v.x); o.y = bf16r(v.y); o.z = bf16r(v.z); o.w = bf16r(v.w);
      out4[idx + j * 262144] = o;
    }
  } else if (b < 2304) {
    // W fp32 -> bf16 (262,144 float4)
    int idx = (b - 2048) * 256 + t;
    const float4* in4 = (const float4*)W;
    ushort4* out4 = (ushort4*)wb;
#pragma unroll
    for (int j = 0; j < 4; ++j) {
      float4 v = in4[idx + j * 65536];
      ushort4 o;
      o.x = bf16r(v.x); o.y = bf16r(v.y); o.z = bf16r(v.z); o.w = bf16r(v.w);
      out4[idx + j * 65536] = o;
    }
  } else {
    // mask flags: fl2[(n*16+qt)*32+kt] = all(mask block 128q x 64k != 0)
    int idx = b - 2304;
    int kt = idx & 31, qt = (idx >> 5) & 15, n = idx >> 9;
    int qr = t >> 1, c8 = t & 1;
    const int4* mp = (const int4*)(mask + (size_t)n * S_LEN * S_LEN +
                                   (size_t)(qt * 128 + qr) * S_LEN + kt * 64) + c8 * 8;
    int ok = 1;
#pragma unroll
    for (int i = 0; i < 8; ++i) {
      int4 m = mp[i];
      ok &= (m.x != 0) & (m.y != 0) & (m.z != 0) & (m.w != 0);
    }
    ok = __all(ok);
    if ((t & 63) == 0) s_ok[t >> 6] = ok;
    __syncthreads();
    if (t == 0) fl2[idx] = (unsigned char)(s_ok[0] & s_ok[1] & s_ok[2] & s_ok[3]);
  }
}

// ---- flash attention: 128 q/block (4 waves x 2 subtiles x 16 q), KVBLK=64 ----
// Swapped QK^T, defer-max, prefetch-double-buffered K/V staging (2-phase pipeline).
__global__ __launch_bounds__(256) void attn_kernel(
    const float* __restrict__ query, const u16* __restrict__ kbuf,
    const u16* __restrict__ vt, const int* __restrict__ mask,
    const unsigned char* __restrict__ fl2, u16* __restrict__ ob) {
  __shared__ __align__(16) unsigned char kl[2][8192];  // K tile [64 k][64 d] dbuf, swizzled
  __shared__ __align__(16) unsigned char vl[2][8192];  // Vt tile [64 d][64 k] dbuf, swizzled
  __shared__ __align__(16) u16 pl[4][2][16][72];       // per wave/u: P[16 q][64 k], pad 72

  int b = blockIdx.x;
  b = (b & 7) * 64 + (b >> 3);  // XCD swizzle: 4 (n,h) pairs per XCD -> K/V L2-resident
  int qt = b & 15, h = (b >> 4) & 15, n = b >> 8;
  int t = threadIdx.x, w = t >> 6, l = t & 63, l16 = l & 15, g = l >> 4;
  int q0w = qt * 128 + w * 32;

  // Q fragments: load fp32, scale by 1/32, convert in-register
  bf16x8 aq[2][2];
#pragma unroll
  for (int u = 0; u < 2; ++u)
#pragma unroll
    for (int hh = 0; hh < 2; ++hh) {
      const float* qp = query + (size_t)(n * S_LEN + q0w + u * 16 + l16) * EMB +
                        h * HD + hh * 32 + g * 8;
      float4 f0 = *(const float4*)qp;
      float4 f1 = *(const float4*)(qp + 4);
      union { bf16x8 v; unsigned int u32[4]; } qq;
      qq.u32[0] = cvt_pk_bf16(f0.x * 0.03125f, f0.y * 0.03125f);
      qq.u32[1] = cvt_pk_bf16(f0.z * 0.03125f, f0.w * 0.03125f);
      qq.u32[2] = cvt_pk_bf16(f1.x * 0.03125f, f1.y * 0.03125f);
      qq.u32[3] = cvt_pk_bf16(f1.z * 0.03125f, f1.w * 0.03125f);
      aq[u][hh] = qq.v;
    }

  f32x4 zero4 = {0.f, 0.f, 0.f, 0.f};
  f32x4 acc[2][4];
  float lrun[2] = {0.f, 0.f}, mrun[2] = {0.f, 0.f}, mL[2] = {0.f, 0.f};
#pragma unroll
  for (int u = 0; u < 2; ++u)
#pragma unroll
    for (int db = 0; db < 4; ++db) acc[u][db] = zero4;

  int row_s = t >> 3, cc = t & 7;
  int sc = cc ^ (row_s & 7);  // pre-swizzled source chunk (rows r and r+32 share r&7)
  const u16* gk0 = kbuf + (size_t)(n * S_LEN + row_s) * EMB + h * HD + sc * 8;
  const u16* gv0 = vt + (size_t)((n * NHEADS + h) * HD + row_s) * S_LEN + sc * 8;

  auto stage = [&](int kt, int nb) {
    const u16* gk = gk0 + (size_t)kt * 64 * EMB;
    const u16* gv = gv0 + kt * 64;
    GLOAD_LDS16(gk, kl[nb] + (w * 64) * 16);
    GLOAD_LDS16(gk + 32 * EMB, kl[nb] + (256 + w * 64) * 16);
    GLOAD_LDS16(gv, vl[nb] + (w * 64) * 16);
    GLOAD_LDS16(gv + 32 * S_LEN, vl[nb] + (256 + w * 64) * 16);
  };

  stage(0, 0);
  __syncthreads();  // drains vmcnt: tile 0 staged

  for (int kt = 0; kt < S_LEN / 64; ++kt) {
    int cur = kt & 1;
    if (kt + 1 < S_LEN / 64) stage(kt + 1, cur ^ 1);  // prefetch next tile
    const unsigned char* kc = kl[cur];
    const unsigned char* vc = vl[cur];

    // S^T = K Q^T : lane (l16,g) -> S[k=kb*16+g*4+r][q=q0w+u*16+l16]
    f32x4 sf[2][4];
    __builtin_amdgcn_s_setprio(1);
#pragma unroll
    for (int kb = 0; kb < 4; ++kb) {
      int row = kb * 16 + l16;
      const unsigned char* kr = kc + row * 128;
      int sw = (row & 7) << 4;
      bf16x8 bk0 = *(const bf16x8*)(kr + ((g * 16) ^ sw));
      bf16x8 bk1 = *(const bf16x8*)(kr + ((64 + g * 16) ^ sw));
#pragma unroll
      for (int u = 0; u < 2; ++u) {
        f32x4 z = zero4;
        z = MFMA16(bk0, aq[u][0], z);
        z = MFMA16(bk1, aq[u][1], z);
        sf[u][kb] = z;
      }
    }
    __builtin_amdgcn_s_setprio(0);

    unsigned char fflag = fl2[((n * 16 + qt) * 32) + kt];
    if (!fflag) {  // rare: per-element mask, k contiguous per lane -> int4
#pragma unroll
      for (int u = 0; u < 2; ++u) {
        const int* mrow = mask + (size_t)n * S_LEN * S_LEN +
                          (size_t)(q0w + u * 16 + l16) * S_LEN + kt * 64 + g * 4;
#pragma unroll
        for (int kb = 0; kb < 4; ++kb) {
          int4 mm = *(const int4*)(mrow + kb * 16);
          if (mm.x == 0) sf[u][kb][0] = -30.f;
          if (mm.y == 0) sf[u][kb][1] = -30.f;
          if (mm.z == 0) sf[u][kb][2] = -30.f;
          if (mm.w == 0) sf[u][kb][3] = -30.f;
        }
      }
    }

#pragma unroll
    for (int u = 0; u < 2; ++u) {
      // defer-max: in-register max over this lane's 16 values (one q-row)
      float lmax = sf[u][0][0];
#pragma unroll
      for (int kb = 0; kb < 4; ++kb)
#pragma unroll
        for (int r = 0; r < 4; ++r) lmax = fmaxf(lmax, sf[u][kb][r]);
      if (!__all(lmax <= mrun[u] + 8.f)) {  // rare rescale path
        float rmax = fmaxf(lmax, __shfl_xor(lmax, 16));
        rmax = fmaxf(rmax, __shfl_xor(rmax, 32));
        float Mn = fmaxf(mrun[u], rmax);
        float corr = fexp2((mrun[u] - Mn) * LOG2E);
        mrun[u] = Mn;
        mL[u] = Mn * LOG2E;
        lrun[u] *= corr;
#pragma unroll
        for (int r = 0; r < 4; ++r) {
          float ca = __shfl(corr, (l & 48) + (g << 2) + r);
#pragma unroll
          for (int db = 0; db < 4; ++db) acc[u][db][r] *= ca;
        }
      }
      // p = exp(s - m), sum into lane-partial, pack to bf16 pairs
      float p[4][4];
#pragma unroll
      for (int kb = 0; kb < 4; ++kb)
#pragma unroll
        for (int r = 0; r < 4; ++r)
          p[kb][r] = fexp2(fmaf(sf[u][kb][r], LOG2E, -mL[u]));
      float s01 = (p[0][0] + p[0][1]) + (p[0][2] + p[0][3]);
      float s23 = (p[1][0] + p[1][1]) + (p[1][2] + p[1][3]);
      float s45 = (p[2][0] + p[2][1]) + (p[2][2] + p[2][3]);
      float s67 = (p[3][0] + p[3][1]) + (p[3][2] + p[3][3]);
      lrun[u] += (s01 + s23) + (s45 + s67);
#pragma unroll
      for (int kb = 0; kb < 4; ++kb) {
        uint2 pw;
        pw.x = cvt_pk_bf16(p[kb][0], p[kb][1]);
        pw.y = cvt_pk_bf16(p[kb][2], p[kb][3]);
        *(uint2*)(&pl[w][u][l16][kb * 16 + g * 4]) = pw;
      }
    }
    __builtin_amdgcn_wave_barrier();  // order P writes before A-frag reads (same wave)

    // O += P V : V fragments shared across both q-subtiles
    __builtin_amdgcn_s_setprio(1);
#pragma unroll
    for (int hh = 0; hh < 2; ++hh) {
      bf16x8 ap0 = *(const bf16x8*)(&pl[w][0][l16][hh * 32 + g * 8]);
      bf16x8 ap1 = *(const bf16x8*)(&pl[w][1][l16][hh * 32 + g * 8]);
#pragma unroll
      for (int db = 0; db < 4; ++db) {
        int d = db * 16 + l16;
        bf16x8 bv = *(const bf16x8*)(vc + d * 128 + ((hh * 64 + g * 16) ^ ((d & 7) << 4)));
        acc[0][db] = MFMA16(ap0, bv, acc[0][db]);
        acc[1][db] = MFMA16(ap1, bv, acc[1][db]);
      }
    }
    __builtin_amdgcn_s_setprio(0);

    __syncthreads();  // drains vmcnt (prefetch landed) + all waves done with cur
  }

  // epilogue: reduce lane-partial sums across g-groups, redistribute to acc rows
#pragma unroll
  for (int u = 0; u < 2; ++u) {
    float s = lrun[u];
    s += __shfl_xor(s, 16);
    s += __shfl_xor(s, 32);
    float rinv[4];
#pragma unroll
    for (int r = 0; r < 4; ++r) {
      float sr = __shfl(s, (l & 48) + (g << 2) + r);
      rinv[r] = 1.f / sr;
    }
#pragma unroll
    for (int db = 0; db < 4; ++db)
#pragma unroll
      for (int r = 0; r < 4; ++r) {
        int qg = q0w + u * 16 + (g << 2) + r;
        ob[(size_t)(n * S_LEN + qg) * EMB + h * HD + db * 16 + l16] =
            bf16r(acc[u][db][r] * rinv[r]);
      }
  }
}

// ---- output projection: C[4096][1024] = O_bf16 @ W_bf16^T + bias ----
// Prefetch-double-buffered staging (2-phase pipeline).
__global__ __launch_bounds__(256) void proj_kernel(
    const u16* __restrict__ A, const u16* __restrict__ Bt,
    const float* __restrict__ bias, float* __restrict__ C) {
  __shared__ __align__(16) unsigned char al[2][16384];
  __shared__ __align__(16) unsigned char bl[2][16384];
  int bm = blockIdx.x, bn = blockIdx.y;
  int t = threadIdx.x, w = t >> 6, l = t & 63;
  int l16 = l & 15, g = l >> 4;
  int wm = w >> 1, wn = w & 1;
  f32x4 zero4 = {0.f, 0.f, 0.f, 0.f};
  f32x4 acc[4][4];
#pragma unroll
  for (int m = 0; m < 4; ++m)
#pragma unroll
    for (int nn = 0; nn < 4; ++nn) acc[m][nn] = zero4;
  int row_s = t >> 3, cc = t & 7;
  int sc = cc ^ (row_s & 7);
  const u16* ga0 = A + (size_t)(bm * 128 + row_s) * EMB + sc * 8;
  const u16* gb0 = Bt + (size_t)(bn * 128 + row_s) * EMB + sc * 8;

  auto stage = [&](int ks, int nb) {
#pragma unroll
    for (int i = 0; i < 4; ++i) {
      GLOAD_LDS16(ga0 + (size_t)i * 32 * EMB + ks * 64, al[nb] + (i * 256 + w * 64) * 16);
      GLOAD_LDS16(gb0 + (size_t)i * 32 * EMB + ks * 64, bl[nb] + (i * 256 + w * 64) * 16);
    }
  };

  stage(0, 0);
  __syncthreads();

  for (int ks = 0; ks < 16; ++ks) {
    int cur = ks & 1;
    if (ks + 1 < 16) stage(ks + 1, cur ^ 1);
    __builtin_amdgcn_s_setprio(1);
#pragma unroll
    for (int hh = 0; hh < 2; ++hh) {
      bf16x8 af[4], bfr[4];
#pragma unroll
      for (int m = 0; m < 4; ++m) {
        int row = wm * 64 + m * 16 + l16;
        af[m] = *(const bf16x8*)(al[cur] + row * 128 + ((hh * 64 + g * 16) ^ ((row & 7) << 4)));
      }
#pragma unroll
      for (int nn = 0; nn < 4; ++nn) {
        int row = wn * 64 + nn * 16 + l16;
        bfr[nn] = *(const bf16x8*)(bl[cur] + row * 128 + ((hh * 64 + g * 16) ^ ((row & 7) << 4)));
      }
#pragma unroll
      for (int m = 0; m < 4; ++m)
#pragma unroll
        for (int nn = 0; nn < 4; ++nn) acc[m][nn] = MFMA16(af[m], bfr[nn], acc[m][nn]);
    }
    __builtin_amdgcn_s_setprio(0);
    __syncthreads();
  }
#pragma unroll
  for (int nn = 0; nn < 4; ++nn) {
    int j = bn * 128 + wn * 64 + nn * 16 + l16;
    float bj = bias[j];
#pragma unroll
    for (int m = 0; m < 4; ++m) {
      int i0 = bm * 128 + wm * 64 + m * 16 + g * 4;
#pragma unroll
      for (int r = 0; r < 4; ++r) C[(size_t)(i0 + r) * EMB + j] = acc[m][nn][r] + bj;
    }
  }
}

extern "C" void kernel_launch(void* const* d_in, const int* in_sizes, int n_in,
                              void* d_out, int out_size, void* d_ws, size_t ws_size,
                              hipStream_t stream) {
  const float* values = (const float*)d_in[0];
  const float* keys = (const float*)d_in[1];
  const float* query = (const float*)d_in[2];
  const int* mask = (const int*)d_in[3];
  const float* W = (const float*)d_in[4];
  const float* bias = (const float*)d_in[5];
  float* out = (float*)d_out;

  u16* kb = (u16*)d_ws;
  u16* vt = kb + 4194304;
  u16* ob = vt + 4194304;
  u16* wb = ob + 4194304;
  unsigned char* fl2 = (unsigned char*)(wb + 1048576);

  prep_kernel<<<3328, 256, 0, stream>>>(values, keys, W, mask, vt, kb, wb, fl2);
  attn_kernel<<<512, 256, 0, stream>>>(query, kb, vt, mask, fl2, ob);
  proj_kernel<<<dim3(32, 8), 256, 0, stream>>>(ob, wb, bias, out);
}

// Round 4
// 96.848 us; speedup vs baseline: 1.8302x; 1.0374x over previous
//
#include <hip/hip_runtime.h>
#include <stdint.h>

// Problem constants (N=2, S=2048, E=1024, H=16, D=64)
#define S_LEN 2048
#define EMB 1024
#define NHEADS 16
#define HD 64
#define LOG2E 1.4426950408889634f

typedef __bf16 bf16x8 __attribute__((ext_vector_type(8)));
typedef float f32x4 __attribute__((ext_vector_type(4)));
typedef unsigned short u16;

#define MFMA16(a, b, c) __builtin_amdgcn_mfma_f32_16x16x32_bf16(a, b, c, 0, 0, 0)
#define GLOAD_LDS16(gp, lp)                                        \
  __builtin_amdgcn_global_load_lds(                                \
      (const __attribute__((address_space(1))) unsigned int*)(gp), \
      (__attribute__((address_space(3))) unsigned int*)(lp), 16, 0, 0)

__device__ __forceinline__ u16 bf16r(float x) {
  union { float f; unsigned int u; } c; c.f = x;
  unsigned int u = c.u + 0x7fffu + ((c.u >> 16) & 1u);
  return (u16)(u >> 16);
}

__device__ __forceinline__ unsigned int cvt_pk_bf16(float lo, float hi) {
  unsigned int r;
  asm("v_cvt_pk_bf16_f32 %0, %1, %2" : "=v"(r) : "v"(lo), "v"(hi));
  return r;
}

__device__ __forceinline__ float fexp2(float x) {
  float r;
  asm("v_exp_f32 %0, %1" : "=v"(r) : "v"(x));
  return r;
}

// k-axis permutation applied to V columns so the PV A-fragment (P) is formed
// from each lane's own QK^T outputs with zero cross-lane traffic.
// QK^T(swapped) lane (l16,g) holds P[q=l16][k=kb*16+g*4+r]; A-frag slot
// (hh,g,e) takes kb=2hh+(e>>2), r=e&3. pos(k) maps physical k -> logical slot.
__device__ __forceinline__ int kperm(int k) {
  int kb = (k >> 4) & 3, g = (k >> 2) & 3, r = k & 3;
  return (kb >> 1) * 32 + g * 8 + (kb & 1) * 4 + r;
}

// ---- fused preprocessing: V-transpose(+k-perm) | K cvt | W cvt | mask flags ----
__global__ __launch_bounds__(256) void prep_kernel(
    const float* __restrict__ values, const float* __restrict__ keys,
    const float* __restrict__ W, const int* __restrict__ mask,
    u16* __restrict__ vt, u16* __restrict__ kb, u16* __restrict__ wb,
    unsigned char* __restrict__ fl2) {
  __shared__ u16 tile[64][65];
  __shared__ int s_ok[4];
  int b = blockIdx.x;
  int t = threadIdx.x;
  if (b < 1024) {
    // V transpose: v[n][s][h*64+d] fp32 -> vt[n][h][d][perm(s)] bf16
    int st = b & 31, h = (b >> 5) & 15, n = b >> 9;
    int s0 = st * 64;
    int d = t & 63, r4 = t >> 6;
#pragma unroll
    for (int i = 0; i < 16; ++i) {
      int s = r4 + i * 4;
      float x = values[(size_t)(n * S_LEN + s0 + s) * EMB + h * HD + d];
      tile[s][d] = bf16r(x);
    }
    __syncthreads();
    int sp = s0 + kperm(d);  // permuted column position
#pragma unroll
    for (int i = 0; i < 16; ++i) {
      int dd = r4 + i * 4;
      vt[(size_t)((n * NHEADS + h) * HD + dd) * S_LEN + sp] = tile[d][dd];
    }
  } else if (b < 2048) {
    // K fp32 -> bf16 (1,048,576 float4)
    int idx = (b - 1024) * 256 + t;
    const float4* in4 = (const float4*)keys;
    ushort4* out4 = (ushort4*)kb;
#pragma unroll
    for (int j = 0; j < 4; ++j) {
      float4 v = in4[idx + j * 262144];
      ushort4 o;
      o.x = bf16r(v.x); o.y = bf16r(v.y); o.z = bf16r(v.z); o.w = bf16r(v.w);
      out4[idx + j * 262144] = o;
    }
  } else if (b < 2304) {
    // W fp32 -> bf16 (262,144 float4)
    int idx = (b - 2048) * 256 + t;
    const float4* in4 = (const float4*)W;
    ushort4* out4 = (ushort4*)wb;
#pragma unroll
    for (int j = 0; j < 4; ++j) {
      float4 v = in4[idx + j * 65536];
      ushort4 o;
      o.x = bf16r(v.x); o.y = bf16r(v.y); o.z = bf16r(v.z); o.w = bf16r(v.w);
      out4[idx + j * 65536] = o;
    }
  } else {
    // mask flags: fl2[(n*16+qt)*32+kt] = all(mask block 128q x 64k != 0)
    int idx = b - 2304;
    int kt = idx & 31, qt = (idx >> 5) & 15, n = idx >> 9;
    int qr = t >> 1, c8 = t & 1;
    const int4* mp = (const int4*)(mask + (size_t)n * S_LEN * S_LEN +
                                   (size_t)(qt * 128 + qr) * S_LEN + kt * 64) + c8 * 8;
    int ok = 1;
#pragma unroll
    for (int i = 0; i < 8; ++i) {
      int4 m = mp[i];
      ok &= (m.x != 0) & (m.y != 0) & (m.z != 0) & (m.w != 0);
    }
    ok = __all(ok);
    if ((t & 63) == 0) s_ok[t >> 6] = ok;
    __syncthreads();
    if (t == 0) fl2[idx] = (unsigned char)(s_ok[0] & s_ok[1] & s_ok[2] & s_ok[3]);
  }
}

// ---- flash attention: 64 q/block (4 waves x 16 q), KVBLK=64, 4 blocks/CU ----
// Swapped QK^T, defer-max, in-register P (k-permuted V), prefetch dbuf staging.
__global__ __launch_bounds__(256, 4) void attn_kernel(
    const float* __restrict__ query, const u16* __restrict__ kbuf,
    const u16* __restrict__ vt, const int* __restrict__ mask,
    const unsigned char* __restrict__ fl2, u16* __restrict__ ob) {
  __shared__ __align__(16) unsigned char kl[2][8192];  // K tile [64 k][64 d] dbuf, swizzled
  __shared__ __align__(16) unsigned char vl[2][8192];  // Vt tile [64 d][64 k'] dbuf, swizzled

  int b = blockIdx.x;
  b = (b & 7) * 128 + (b >> 3);  // XCD swizzle: 4 (n,h) groups per XCD -> K/V L2-resident
  int qt = b & 31, h = (b >> 5) & 15, n = b >> 9;
  int t = threadIdx.x, w = t >> 6, l = t & 63, l16 = l & 15, g = l >> 4;
  int q0w = qt * 64 + w * 16;

  // Q fragment (B-operand of swapped QK): load fp32, scale 1/32, convert in-register
  bf16x8 aq[2];
#pragma unroll
  for (int hh = 0; hh < 2; ++hh) {
    const float* qp = query + (size_t)(n * S_LEN + q0w + l16) * EMB + h * HD + hh * 32 + g * 8;
    float4 f0 = *(const float4*)qp;
    float4 f1 = *(const float4*)(qp + 4);
    union { bf16x8 v; unsigned int u32[4]; } qq;
    qq.u32[0] = cvt_pk_bf16(f0.x * 0.03125f, f0.y * 0.03125f);
    qq.u32[1] = cvt_pk_bf16(f0.z * 0.03125f, f0.w * 0.03125f);
    qq.u32[2] = cvt_pk_bf16(f1.x * 0.03125f, f1.y * 0.03125f);
    qq.u32[3] = cvt_pk_bf16(f1.z * 0.03125f, f1.w * 0.03125f);
    aq[hh] = qq.v;
  }

  f32x4 zero4 = {0.f, 0.f, 0.f, 0.f};
  f32x4 acc[4];
  float lrun = 0.f, mrun = 0.f, mL = 0.f;
#pragma unroll
  for (int db = 0; db < 4; ++db) acc[db] = zero4;

  int row_s = t >> 3, cc = t & 7;
  int sc = cc ^ (row_s & 7);  // pre-swizzled source chunk (rows r and r+32 share r&7)
  const u16* gk0 = kbuf + (size_t)(n * S_LEN + row_s) * EMB + h * HD + sc * 8;
  const u16* gv0 = vt + (size_t)((n * NHEADS + h) * HD + row_s) * S_LEN + sc * 8;

  auto stage = [&](int kt, int nb) {
    const u16* gk = gk0 + (size_t)kt * 64 * EMB;
    const u16* gv = gv0 + kt * 64;
    GLOAD_LDS16(gk, kl[nb] + (w * 64) * 16);
    GLOAD_LDS16(gk + 32 * EMB, kl[nb] + (256 + w * 64) * 16);
    GLOAD_LDS16(gv, vl[nb] + (w * 64) * 16);
    GLOAD_LDS16(gv + 32 * S_LEN, vl[nb] + (256 + w * 64) * 16);
  };

  stage(0, 0);
  __syncthreads();  // tile 0 staged

  for (int kt = 0; kt < S_LEN / 64; ++kt) {
    int cur = kt & 1;
    if (kt + 1 < S_LEN / 64) stage(kt + 1, cur ^ 1);  // prefetch next tile
    const unsigned char* kc = kl[cur];
    const unsigned char* vc = vl[cur];

    // S^T = K Q^T : lane (l16,g) -> S[k=kb*16+g*4+r][q=q0w+l16]
    f32x4 sf[4];
    __builtin_amdgcn_s_setprio(1);
#pragma unroll
    for (int kb = 0; kb < 4; ++kb) {
      int row = kb * 16 + l16;
      const unsigned char* kr = kc + row * 128;
      int sw = (row & 7) << 4;
      bf16x8 bk0 = *(const bf16x8*)(kr + ((g * 16) ^ sw));
      bf16x8 bk1 = *(const bf16x8*)(kr + ((64 + g * 16) ^ sw));
      f32x4 z = zero4;
      z = MFMA16(bk0, aq[0], z);
      z = MFMA16(bk1, aq[1], z);
      sf[kb] = z;
    }
    __builtin_amdgcn_s_setprio(0);

    unsigned char fflag = fl2[((n * 16 + (qt >> 1)) * 32) + kt];
    if (!fflag) {  // rare: per-element mask, k contiguous per lane -> int4
      const int* mrow = mask + (size_t)n * S_LEN * S_LEN +
                        (size_t)(q0w + l16) * S_LEN + kt * 64 + g * 4;
#pragma unroll
      for (int kb = 0; kb < 4; ++kb) {
        int4 mm = *(const int4*)(mrow + kb * 16);
        if (mm.x == 0) sf[kb][0] = -30.f;
        if (mm.y == 0) sf[kb][1] = -30.f;
        if (mm.z == 0) sf[kb][2] = -30.f;
        if (mm.w == 0) sf[kb][3] = -30.f;
      }
    }

    // defer-max: in-register max over this lane's 16 values (one q-row)
    float lmax = sf[0][0];
#pragma unroll
    for (int kb = 0; kb < 4; ++kb)
#pragma unroll
      for (int r = 0; r < 4; ++r) lmax = fmaxf(lmax, sf[kb][r]);
    if (!__all(lmax <= mrun + 8.f)) {  // rare rescale path
      float rmax = fmaxf(lmax, __shfl_xor(lmax, 16));
      rmax = fmaxf(rmax, __shfl_xor(rmax, 32));
      float Mn = fmaxf(mrun, rmax);
      float corr = fexp2((mrun - Mn) * LOG2E);
      mrun = Mn;
      mL = Mn * LOG2E;
      lrun *= corr;
#pragma unroll
      for (int r = 0; r < 4; ++r) {
        float ca = __shfl(corr, (l & 48) + (g << 2) + r);
#pragma unroll
        for (int db = 0; db < 4; ++db) acc[db][r] *= ca;
      }
    }
    // p = exp(s - m), lane-partial sum, pack A-fragments in-register (k-perm)
    float p[4][4];
#pragma unroll
    for (int kb = 0; kb < 4; ++kb)
#pragma unroll
      for (int r = 0; r < 4; ++r)
        p[kb][r] = fexp2(fmaf(sf[kb][r], LOG2E, -mL));
    float s01 = (p[0][0] + p[0][1]) + (p[0][2] + p[0][3]);
    float s23 = (p[1][0] + p[1][1]) + (p[1][2] + p[1][3]);
    float s45 = (p[2][0] + p[2][1]) + (p[2][2] + p[2][3]);
    float s67 = (p[3][0] + p[3][1]) + (p[3][2] + p[3][3]);
    lrun += (s01 + s23) + (s45 + s67);

    bf16x8 pa[2];
#pragma unroll
    for (int hh = 0; hh < 2; ++hh) {
      union { bf16x8 v; unsigned int u32[4]; } pp;
      pp.u32[0] = cvt_pk_bf16(p[2 * hh][0], p[2 * hh][1]);
      pp.u32[1] = cvt_pk_bf16(p[2 * hh][2], p[2 * hh][3]);
      pp.u32[2] = cvt_pk_bf16(p[2 * hh + 1][0], p[2 * hh + 1][1]);
      pp.u32[3] = cvt_pk_bf16(p[2 * hh + 1][2], p[2 * hh + 1][3]);
      pa[hh] = pp.v;
    }

    // O += P V : A = in-register P, B = permuted Vt rows (ds_read_b128)
    __builtin_amdgcn_s_setprio(1);
#pragma unroll
    for (int hh = 0; hh < 2; ++hh)
#pragma unroll
      for (int db = 0; db < 4; ++db) {
        int d = db * 16 + l16;
        bf16x8 bv = *(const bf16x8*)(vc + d * 128 + ((hh * 64 + g * 16) ^ ((d & 7) << 4)));
        acc[db] = MFMA16(pa[hh], bv, acc[db]);
      }
    __builtin_amdgcn_s_setprio(0);

    __syncthreads();  // all waves done reading cur; prefetch (cur^1) landed
  }

  // epilogue: reduce lane-partial sums across g-groups, redistribute to acc rows
  float s = lrun;
  s += __shfl_xor(s, 16);
  s += __shfl_xor(s, 32);
  float rinv[4];
#pragma unroll
  for (int r = 0; r < 4; ++r) {
    float sr = __shfl(s, (l & 48) + (g << 2) + r);
    rinv[r] = 1.f / sr;
  }
#pragma unroll
  for (int db = 0; db < 4; ++db)
#pragma unroll
    for (int r = 0; r < 4; ++r) {
      int qg = q0w + (g << 2) + r;
      ob[(size_t)(n * S_LEN + qg) * EMB + h * HD + db * 16 + l16] =
          bf16r(acc[db][r] * rinv[r]);
    }
}

// ---- output projection: C[4096][1024] = O_bf16 @ W_bf16^T + bias ----
// Prefetch-double-buffered staging (2-phase pipeline).
__global__ __launch_bounds__(256) void proj_kernel(
    const u16* __restrict__ A, const u16* __restrict__ Bt,
    const float* __restrict__ bias, float* __restrict__ C) {
  __shared__ __align__(16) unsigned char al[2][16384];
  __shared__ __align__(16) unsigned char bl[2][16384];
  int bm = blockIdx.x, bn = blockIdx.y;
  int t = threadIdx.x, w = t >> 6, l = t & 63;
  int l16 = l & 15, g = l >> 4;
  int wm = w >> 1, wn = w & 1;
  f32x4 zero4 = {0.f, 0.f, 0.f, 0.f};
  f32x4 acc[4][4];
#pragma unroll
  for (int m = 0; m < 4; ++m)
#pragma unroll
    for (int nn = 0; nn < 4; ++nn) acc[m][nn] = zero4;
  int row_s = t >> 3, cc = t & 7;
  int sc = cc ^ (row_s & 7);
  const u16* ga0 = A + (size_t)(bm * 128 + row_s) * EMB + sc * 8;
  const u16* gb0 = Bt + (size_t)(bn * 128 + row_s) * EMB + sc * 8;

  auto stage = [&](int ks, int nb) {
#pragma unroll
    for (int i = 0; i < 4; ++i) {
      GLOAD_LDS16(ga0 + (size_t)i * 32 * EMB + ks * 64, al[nb] + (i * 256 + w * 64) * 16);
      GLOAD_LDS16(gb0 + (size_t)i * 32 * EMB + ks * 64, bl[nb] + (i * 256 + w * 64) * 16);
    }
  };

  stage(0, 0);
  __syncthreads();

  for (int ks = 0; ks < 16; ++ks) {
    int cur = ks & 1;
    if (ks + 1 < 16) stage(ks + 1, cur ^ 1);
    __builtin_amdgcn_s_setprio(1);
#pragma unroll
    for (int hh = 0; hh < 2; ++hh) {
      bf16x8 af[4], bfr[4];
#pragma unroll
      for (int m = 0; m < 4; ++m) {
        int row = wm * 64 + m * 16 + l16;
        af[m] = *(const bf16x8*)(al[cur] + row * 128 + ((hh * 64 + g * 16) ^ ((row & 7) << 4)));
      }
#pragma unroll
      for (int nn = 0; nn < 4; ++nn) {
        int row = wn * 64 + nn * 16 + l16;
        bfr[nn] = *(const bf16x8*)(bl[cur] + row * 128 + ((hh * 64 + g * 16) ^ ((row & 7) << 4)));
      }
#pragma unroll
      for (int m = 0; m < 4; ++m)
#pragma unroll
        for (int nn = 0; nn < 4; ++nn) acc[m][nn] = MFMA16(af[m], bfr[nn], acc[m][nn]);
    }
    __builtin_amdgcn_s_setprio(0);
    __syncthreads();
  }
#pragma unroll
  for (int nn = 0; nn < 4; ++nn) {
    int j = bn * 128 + wn * 64 + nn * 16 + l16;
    float bj = bias[j];
#pragma unroll
    for (int m = 0; m < 4; ++m) {
      int i0 = bm * 128 + wm * 64 + m * 16 + g * 4;
#pragma unroll
      for (int r = 0; r < 4; ++r) C[(size_t)(i0 + r) * EMB + j] = acc[m][nn][r] + bj;
    }
  }
}

extern "C" void kernel_launch(void* const* d_in, const int* in_sizes, int n_in,
                              void* d_out, int out_size, void* d_ws, size_t ws_size,
                              hipStream_t stream) {
  const float* values = (const float*)d_in[0];
  const float* keys = (const float*)d_in[1];
  const float* query = (const float*)d_in[2];
  const int* mask = (const int*)d_in[3];
  const float* W = (const float*)d_in[4];
  const float* bias = (const float*)d_in[5];
  float* out = (float*)d_out;

  u16* kb = (u16*)d_ws;
  u16* vt = kb + 4194304;
  u16* ob = vt + 4194304;
  u16* wb = ob + 4194304;
  unsigned char* fl2 = (unsigned char*)(wb + 1048576);

  prep_kernel<<<3328, 256, 0, stream>>>(values, keys, W, mask, vt, kb, wb, fl2);
  attn_kernel<<<1024, 256, 0, stream>>>(query, kb, vt, mask, fl2, ob);
  proj_kernel<<<dim3(32, 8), 256, 0, stream>>>(ob, wb, bias, out);
}